// Round 3
// baseline (138.267 us; speedup 1.0000x reference)
//
#include <hip/hip_runtime.h>
#include <math.h>

#define NG 128
#define NIN 512
#define OFF1 4194304   // 8192*512
#define OFF2 8388608   // 2*8192*512
#define OFF3 9437184   // OFF2 + 8192*128

#define INV_SQRT_2PI 0.3989422804014327f
#define INV_SQRT2    0.7071067811865476f

// fast tanh: 1 - 2/(e^{2x}+1). v_exp_f32 + v_rcp_f32, ~2ulp.
__device__ __forceinline__ float ftanh(float x){
    float e = __expf(2.0f*x);
    float r = __builtin_amdgcn_rcpf(e + 1.0f);
    return 1.0f - 2.0f*r;
}
__device__ __forceinline__ float frcp(float x){ return __builtin_amdgcn_rcpf(x); }

__device__ __forceinline__ float gelu_f(float x){
    return 0.5f*x*(1.0f + erff(x*INV_SQRT2));
}
__device__ __forceinline__ float gelu_df(float x){
    return 0.5f*(1.0f + erff(x*INV_SQRT2)) + x*INV_SQRT_2PI*__expf(-0.5f*x*x);
}

// Fused kernel: forward + grad + Hessian contractions + dS/dt partials.
// 2048 blocks x 256 threads; thread = (g = tid&127) x 2 batch rows.
__global__ __launch_bounds__(256) void k_fused(const float* __restrict__ z,
    const float* __restrict__ ts,
    const float* __restrict__ mup, const float* __restrict__ sigp,
    const float* __restrict__ Wx, const float* __restrict__ bx,
    const float* __restrict__ Wt, const float* __restrict__ bt,
    const float* __restrict__ Wt2, const float* __restrict__ bt2,
    const float* __restrict__ Wf, const float* __restrict__ bf,
    const float* __restrict__ Wo, const float* __restrict__ bo,
    const float* __restrict__ betap,
    float* __restrict__ partial, float* __restrict__ out){
    const int tid  = threadIdx.x;
    const int gidx = tid & 127;
    const int lb   = tid >> 7;

    // ---- truncnorm scalar constants (inline; erf amortized over 2 rows) ----
    const float mu = mup[0], sigma = sigp[0];
    const float sig2     = sigma*sigma + 1e-5f;
    const float inv_sig2 = frcp(sig2);
    const float dlp      = -inv_sig2;
    const float inv_s4   = frcp(sigma*sigma*sigma*sigma + 1e-5f);
    const float inv_sig  = frcp(sigma);
    const float phi_b    = 0.5f*(1.0f+erff((10.0f-mu)*inv_sig*INV_SQRT2));
    const float phi_a    = 0.5f*(1.0f+erff((-10.0f-mu)*inv_sig*INV_SQRT2));
    const float invZ     = frcp(phi_b-phi_a);

    // ---- weights for this group ----
    float wx[16], wf[16];
    #pragma unroll
    for (int i=0;i<4;i++){
        float4 a4 = ((const float4*)(Wx + gidx*16))[i];
        wx[i*4+0]=a4.x; wx[i*4+1]=a4.y; wx[i*4+2]=a4.z; wx[i*4+3]=a4.w;
        float4 b4 = ((const float4*)(Wf + gidx*16))[i];
        wf[i*4+0]=b4.x; wf[i*4+1]=b4.y; wf[i*4+2]=b4.z; wf[i*4+3]=b4.w;
    }
    float4 t4;
    t4 = ((const float4*)bx)[gidx];    float bxA[4]={t4.x,t4.y,t4.z,t4.w};
    t4 = ((const float4*)bf)[gidx];    float bfA[4]={t4.x,t4.y,t4.z,t4.w};
    t4 = ((const float4*)Wo)[gidx];    float w3[4] ={t4.x,t4.y,t4.z,t4.w};
    const float bo0 = bo[gidx];
    const float bb  = betap[gidx];

    // ---- tv(t), dtv/dt inline (was k_pre): freqs = [1, 0.01] exactly ----
    float tvA[4], dtvA[4];
    {
        const float t  = ts[0];
        const float f1 = 0.01f;
        float te0 = t, te1 = t*f1;
        float s0, c0, s1, c1;
        __sincosf(te0, &s0, &c0);
        __sincosf(te1, &s1, &c1);
        float temb[4]  = { s0, s1, c0, c1 };
        float dtemb[4] = { c0, f1*c1, -s0, -f1*s1 };
        float tg[4], dg[4];
        #pragma unroll
        for (int i=0;i<4;i++){
            float a = bt[gidx*4+i], d = 0.0f;
            #pragma unroll
            for (int j=0;j<4;j++){
                float w = Wt[gidx*16+i*4+j];
                a += w*temb[j]; d += w*dtemb[j];
            }
            tg[i] = gelu_f(a);
            dg[i] = gelu_df(a)*d;
        }
        #pragma unroll
        for (int j=0;j<4;j++){
            float a = bt2[gidx*4+j], d = 0.0f;
            #pragma unroll
            for (int i=0;i<4;i++){
                float w = Wt2[gidx*16+j*4+i];
                a += w*tg[i]; d += w*dg[i];
            }
            tvA[j]  = a;
            dtvA[j] = d;
        }
    }

    float dsdt_acc = 0.0f;
    const int b_base = blockIdx.x*4 + lb*2;

    for (int r=0;r<2;r++){
        const int b = b_base + r;
        float4 zv = *((const float4*)(z + b*NIN + gidx*4));
        float zz[4]={zv.x,zv.y,zv.z,zv.w};

        // forward
        float x[4], xp[4], u1[4];
        #pragma unroll
        for (int i=0;i<4;i++){
            float a = bxA[i] + wx[i*4]*zz[0]+wx[i*4+1]*zz[1]+wx[i*4+2]*zz[2]+wx[i*4+3]*zz[3];
            x[i] = ftanh(a); xp[i] = 1.0f - x[i]*x[i];
            u1[i] = x[i] + tvA[i];
        }
        float h[4], hp[4];
        float a3 = bo0;
        #pragma unroll
        for (int i=0;i<4;i++){
            float a = bfA[i] + wf[i*4]*u1[0]+wf[i*4+1]*u1[1]+wf[i*4+2]*u1[2]+wf[i*4+3]*u1[3];
            h[i] = ftanh(a); hp[i] = 1.0f - h[i]*h[i];
            a3 += w3[i]*h[i];
        }
        float S = ftanh(a3), sp = 1.0f - S*S;

        // B[i,n] = sum_k Wf[i,k]*xp_k*Wx[k,n]
        float Bm[16];
        #pragma unroll
        for (int i=0;i<4;i++){
            #pragma unroll
            for (int n=0;n<4;n++){
                float s = 0.0f;
                #pragma unroll
                for (int k=0;k<4;k++) s += wf[i*4+k]*xp[k]*wx[k*4+n];
                Bm[i*4+n]=s;
            }
        }
        float w3hp[4], v[4];
        #pragma unroll
        for (int i=0;i<4;i++){ w3hp[i]=w3[i]*hp[i]; v[i]=sp*w3hp[i]; }
        float q[4]={0.f,0.f,0.f,0.f};
        #pragma unroll
        for (int i=0;i<4;i++){
            #pragma unroll
            for (int j=0;j<4;j++) q[j] += v[i]*wf[i*4+j];
        }
        dsdt_acc += q[0]*dtvA[0]+q[1]*dtvA[1]+q[2]*dtvA[2]+q[3]*dtvA[3];

        float c[4];
        #pragma unroll
        for (int n=0;n<4;n++){
            float s=0.0f;
            #pragma unroll
            for (int i=0;i<4;i++) s += w3hp[i]*Bm[i*4+n];
            c[n]=s;
        }
        const float alpha = -2.0f*S*sp;
        float bet[4], gam[4];
        #pragma unroll
        for (int i=0;i<4;i++){ bet[i] = -2.0f*h[i]*v[i]; gam[i] = -2.0f*x[i]*xp[i]*q[i]; }

        // rho / nlp / dpp
        float rho[4], nlp[4], dpp[4];
        #pragma unroll
        for (int j=0;j<4;j++){
            float zj = zz[j];
            float xs = zj > 10.0f ? zj+100.0f : zj;
            xs = xs < -10.0f ? xs-100.0f : xs;
            float xn = (xs-mu)*inv_sig;
            float dens = __expf(-0.5f*xn*xn)*INV_SQRT_2PI;
            dens = (xn > 10.0f || xn < -10.0f) ? 0.0f : dens;
            rho[j] = dens*invZ + 1e-10f;
            nlp[j] = -(zj-mu)*inv_sig2;
            float d = zj-mu;
            dpp[j] = (d*d - sigma*sigma)*inv_s4;
        }
        float u_val = S - bb*__logf(rho[0]*rho[1]*rho[2]*rho[3]);

        // contractions: H = alpha c c^T + sum_i bet_i B_i B_i^T + sum_k gam_k A_k A_k^T
        float rc=0.0f, scs=0.0f;
        #pragma unroll
        for (int j=0;j<4;j++){ rc += rho[j]*c[j]; scs += c[j]; }
        float rB[4], sB[4], rA[4], sA[4];
        #pragma unroll
        for (int i=0;i<4;i++){
            float r1=0.0f, s=0.0f, r2=0.0f, s2=0.0f;
            #pragma unroll
            for (int j=0;j<4;j++){
                r1 += rho[j]*Bm[i*4+j]; s  += Bm[i*4+j];
                r2 += rho[j]*wx[i*4+j]; s2 += wx[i*4+j];
            }
            rB[i]=r1; sB[i]=s; rA[i]=r2; sA[i]=s2;
        }

        float pde[4], uz[4], uzz[4];
        #pragma unroll
        for (int k=0;k<4;k++){
            float corr = alpha*rc*c[k];
            float hsum = alpha*scs*c[k];
            #pragma unroll
            for (int i=0;i<4;i++){
                corr += bet[i]*rB[i]*Bm[i*4+k];
                hsum += bet[i]*sB[i]*Bm[i*4+k];
                corr += gam[i]*rA[i]*wx[i*4+k];
                hsum += gam[i]*sA[i]*wx[i*4+k];
            }
            float uzk = sp*c[k] - bb*nlp[k];
            uz[k]  = uzk;
            uzz[k] = hsum - bb*dlp;
            // pde WITHOUT the dSdt_sum broadcast term (k_fix adds it)
            pde[k] = bb*corr*frcp(rho[k]+1e-5f)
                   + 0.5f*uzk*uzk + 0.125f*bb*bb*(nlp[k]*nlp[k] - 2.0f*dpp[k]);
        }

        const int base = b*NIN + gidx*4;
        *((float4*)(out + base))        = make_float4(pde[0],pde[1],pde[2],pde[3]);
        *((float4*)(out + OFF1 + base)) = make_float4(uz[0],uz[1],uz[2],uz[3]);
        out[OFF2 + b*NG + gidx] = u_val;
        *((float4*)(out + OFF3 + base)) = make_float4(uzz[0],uzz[1],uzz[2],uzz[3]);
    }

    __shared__ float sred[256];
    sred[tid] = dsdt_acc;
    __syncthreads();
    if (tid < 128) partial[blockIdx.x*128 + tid] = sred[tid] + sred[tid+128];
}

// Reduce 2048 partials per group -> dsum[g]. 128 blocks x 256 threads.
__global__ __launch_bounds__(256) void k_red(const float* __restrict__ partial,
                                             float* __restrict__ dsum){
    int g = blockIdx.x;
    int tid = threadIdx.x;
    float a = 0.0f;
    for (int i=tid;i<2048;i+=256) a += partial[i*128+g];
    __shared__ float s[256];
    s[tid] = a;
    __syncthreads();
    if (tid < 64){
        a = s[tid] + s[tid+64] + s[tid+128] + s[tid+192];
        #pragma unroll
        for (int o=32;o>0;o>>=1) a += __shfl_down(a, o);
        if (tid==0) dsum[g] = a;
    }
}

// pde += dsum[g]. 4096 blocks x 256 threads, one float4 per thread.
__global__ __launch_bounds__(256) void k_fix(const float* __restrict__ dsum,
                                             float* __restrict__ out){
    const int idx = blockIdx.x*256 + threadIdx.x;   // float4 index; g = idx&127
    const float ds = dsum[threadIdx.x & 127];
    float4* p = ((float4*)out) + idx;
    float4 v = *p;
    v.x += ds; v.y += ds; v.z += ds; v.w += ds;
    *p = v;
}

extern "C" void kernel_launch(void* const* d_in, const int* in_sizes, int n_in,
                              void* d_out, int out_size, void* d_ws, size_t ws_size,
                              hipStream_t stream){
    (void)in_sizes; (void)n_in; (void)out_size; (void)ws_size;
    const float* z     = (const float*)d_in[0];
    const float* ts    = (const float*)d_in[1];
    const float* mu    = (const float*)d_in[2];
    const float* sigma = (const float*)d_in[3];
    const float* Wx    = (const float*)d_in[4];
    const float* bx    = (const float*)d_in[5];
    const float* Wt    = (const float*)d_in[6];
    const float* bt    = (const float*)d_in[7];
    const float* Wt2   = (const float*)d_in[8];
    const float* bt2   = (const float*)d_in[9];
    const float* Wf    = (const float*)d_in[10];
    const float* bf    = (const float*)d_in[11];
    const float* Wo    = (const float*)d_in[12];
    const float* bo    = (const float*)d_in[13];
    const float* beta  = (const float*)d_in[14];
    float* out = (float*)d_out;

    float* ws      = (float*)d_ws;
    float* dsum    = ws;            // 128
    float* partial = ws + 128;      // 2048*128 = 262144 (1 MB)

    k_fused<<<2048,256, 0, stream>>>(z, ts, mu, sigma, Wx, bx, Wt, bt, Wt2, bt2,
                                     Wf, bf, Wo, bo, beta, partial, out);
    k_red  <<<128, 256, 0, stream>>>(partial, dsum);
    k_fix  <<<4096,256, 0, stream>>>(dsum, out);
}

// Round 4
// 129.478 us; speedup vs baseline: 1.0679x; 1.0679x over previous
//
#include <hip/hip_runtime.h>
#include <math.h>

#define NG 128
#define NIN 512
#define OFF1 4194304   // 8192*512
#define OFF2 8388608   // 2*8192*512
#define OFF3 9437184   // OFF2 + 8192*128

#define INV_SQRT_2PI 0.3989422804014327f
#define INV_SQRT2    0.7071067811865476f

typedef float f32x4 __attribute__((ext_vector_type(4)));

// fast tanh: 1 - 2/(e^{2x}+1). v_exp_f32 + v_rcp_f32, ~2ulp.
__device__ __forceinline__ float ftanh(float x){
    float e = __expf(2.0f*x);
    float r = __builtin_amdgcn_rcpf(e + 1.0f);
    return 1.0f - 2.0f*r;
}
__device__ __forceinline__ float frcp(float x){ return __builtin_amdgcn_rcpf(x); }

__device__ __forceinline__ float gelu_f(float x){
    return 0.5f*x*(1.0f + erff(x*INV_SQRT2));
}
__device__ __forceinline__ float gelu_df(float x){
    return 0.5f*(1.0f + erff(x*INV_SQRT2)) + x*INV_SQRT_2PI*__expf(-0.5f*x*x);
}

// Kernel 1: per-group tv(t), d tv/dt, truncnorm scalar constants.
// All the expensive OCML (erf, sincos) lives here: 1 block, runs once.
__global__ void k_pre(const float* __restrict__ ts,
                      const float* __restrict__ mup, const float* __restrict__ sigp,
                      const float* __restrict__ Wt,  const float* __restrict__ bt,
                      const float* __restrict__ Wt2, const float* __restrict__ bt2,
                      float* __restrict__ tv_ws, float* __restrict__ dtv_ws,
                      float* __restrict__ consts){
    int g = threadIdx.x;
    if (g == 0){
        float mu = mup[0], sigma = sigp[0];
        float sig2   = sigma*sigma + 1e-5f;
        float phi_b  = 0.5f*(1.0f+erff((10.0f-mu)/sigma*INV_SQRT2));
        float phi_a  = 0.5f*(1.0f+erff((-10.0f-mu)/sigma*INV_SQRT2));
        consts[0] = sig2;
        consts[1] = -1.0f/sig2;                                    // dlp
        consts[2] = 1.0f/(sigma*sigma*sigma*sigma + 1e-5f);        // inv_s4
        consts[3] = 1.0f/(phi_b-phi_a);                            // invZ
        consts[4] = mu;
        consts[5] = 1.0f/sigma;
        consts[6] = sigma;
    }
    if (g >= NG) return;
    float t  = ts[0];
    const float f1 = 0.01f;                     // freqs = [1, 0.01] exactly
    float s0, c0, s1, c1;
    __sincosf(t, &s0, &c0);
    __sincosf(t*f1, &s1, &c1);
    float temb[4]  = { s0, s1, c0, c1 };
    float dtemb[4] = { c0, f1*c1, -s0, -f1*s1 };
    float tg[4], dg[4];
    #pragma unroll
    for (int i=0;i<4;i++){
        float a = bt[g*4+i], d = 0.0f;
        #pragma unroll
        for (int j=0;j<4;j++){
            float w = Wt[g*16+i*4+j];
            a += w*temb[j]; d += w*dtemb[j];
        }
        tg[i] = gelu_f(a);
        dg[i] = gelu_df(a)*d;
    }
    #pragma unroll
    for (int j=0;j<4;j++){
        float a = bt2[g*4+j], d = 0.0f;
        #pragma unroll
        for (int i=0;i<4;i++){
            float w = Wt2[g*16+j*4+i];
            a += w*tg[i]; d += w*dg[i];
        }
        tv_ws[g*4+j]  = a;
        dtv_ws[g*4+j] = d;
    }
}

// Main kernel: 4096 blocks x 256 threads; thread = one (b, group).
// Writes pde (minus dSdt broadcast), u_z, u, u_zz; block-reduces dS/dt partials.
__global__ __launch_bounds__(256) void k_main(const float* __restrict__ z,
    const float* __restrict__ Wx, const float* __restrict__ bx,
    const float* __restrict__ Wf, const float* __restrict__ bf,
    const float* __restrict__ Wo, const float* __restrict__ bo,
    const float* __restrict__ betap, const float* __restrict__ tv_ws,
    const float* __restrict__ dtv_ws, const float* __restrict__ consts,
    float* __restrict__ partial, float* __restrict__ out){
    const int tid  = threadIdx.x;
    const int gidx = tid & 127;
    const int b    = blockIdx.x*2 + (tid>>7);

    // uniform scalar loads (s_load)
    const float sig2    = consts[0];
    const float dlp     = consts[1];
    const float inv_s4  = consts[2];
    const float invZ    = consts[3];
    const float mu      = consts[4];
    const float inv_sig = consts[5];
    const float sigma   = consts[6];
    const float inv_sig2 = frcp(sig2);

    float wx[16], wf[16];
    #pragma unroll
    for (int i=0;i<4;i++){
        float4 a4 = ((const float4*)(Wx + gidx*16))[i];
        wx[i*4+0]=a4.x; wx[i*4+1]=a4.y; wx[i*4+2]=a4.z; wx[i*4+3]=a4.w;
        float4 b4 = ((const float4*)(Wf + gidx*16))[i];
        wf[i*4+0]=b4.x; wf[i*4+1]=b4.y; wf[i*4+2]=b4.z; wf[i*4+3]=b4.w;
    }
    float4 t4;
    t4 = ((const float4*)bx)[gidx];     float bxA[4]={t4.x,t4.y,t4.z,t4.w};
    t4 = ((const float4*)bf)[gidx];     float bfA[4]={t4.x,t4.y,t4.z,t4.w};
    t4 = ((const float4*)Wo)[gidx];     float w3[4] ={t4.x,t4.y,t4.z,t4.w};
    t4 = ((const float4*)tv_ws)[gidx];  float tvA[4]={t4.x,t4.y,t4.z,t4.w};
    t4 = ((const float4*)dtv_ws)[gidx]; float dtvA[4]={t4.x,t4.y,t4.z,t4.w};
    const float bo0 = bo[gidx];
    const float bb  = betap[gidx];

    float4 zv = *((const float4*)(z + b*NIN + gidx*4));
    float zz[4]={zv.x,zv.y,zv.z,zv.w};

    // forward
    float x[4], xp[4], u1[4];
    #pragma unroll
    for (int i=0;i<4;i++){
        float a = bxA[i] + wx[i*4]*zz[0]+wx[i*4+1]*zz[1]+wx[i*4+2]*zz[2]+wx[i*4+3]*zz[3];
        x[i] = ftanh(a); xp[i] = 1.0f - x[i]*x[i];
        u1[i] = x[i] + tvA[i];
    }
    float h[4], hp[4];
    float a3 = bo0;
    #pragma unroll
    for (int i=0;i<4;i++){
        float a = bfA[i] + wf[i*4]*u1[0]+wf[i*4+1]*u1[1]+wf[i*4+2]*u1[2]+wf[i*4+3]*u1[3];
        h[i] = ftanh(a); hp[i] = 1.0f - h[i]*h[i];
        a3 += w3[i]*h[i];
    }
    float S = ftanh(a3), sp = 1.0f - S*S;

    // B[i,n] = sum_k Wf[i,k]*xp_k*Wx[k,n]
    float Bm[16];
    #pragma unroll
    for (int i=0;i<4;i++){
        #pragma unroll
        for (int n=0;n<4;n++){
            float s = 0.0f;
            #pragma unroll
            for (int k=0;k<4;k++) s += wf[i*4+k]*xp[k]*wx[k*4+n];
            Bm[i*4+n]=s;
        }
    }
    float w3hp[4], v[4];
    #pragma unroll
    for (int i=0;i<4;i++){ w3hp[i]=w3[i]*hp[i]; v[i]=sp*w3hp[i]; }
    float q[4]={0.f,0.f,0.f,0.f};
    #pragma unroll
    for (int i=0;i<4;i++){
        #pragma unroll
        for (int j=0;j<4;j++) q[j] += v[i]*wf[i*4+j];
    }
    float dsdt_acc = q[0]*dtvA[0]+q[1]*dtvA[1]+q[2]*dtvA[2]+q[3]*dtvA[3];

    float c[4];
    #pragma unroll
    for (int n=0;n<4;n++){
        float s=0.0f;
        #pragma unroll
        for (int i=0;i<4;i++) s += w3hp[i]*Bm[i*4+n];
        c[n]=s;
    }
    const float alpha = -2.0f*S*sp;
    float bet[4], gam[4];
    #pragma unroll
    for (int i=0;i<4;i++){ bet[i] = -2.0f*h[i]*v[i]; gam[i] = -2.0f*x[i]*xp[i]*q[i]; }

    // rho / nlp / dpp
    float rho[4], nlp[4], dpp[4];
    #pragma unroll
    for (int j=0;j<4;j++){
        float zj = zz[j];
        float xs = zj > 10.0f ? zj+100.0f : zj;
        xs = xs < -10.0f ? xs-100.0f : xs;
        float xn = (xs-mu)*inv_sig;
        float dens = __expf(-0.5f*xn*xn)*INV_SQRT_2PI;
        dens = (xn > 10.0f || xn < -10.0f) ? 0.0f : dens;
        rho[j] = dens*invZ + 1e-10f;
        nlp[j] = -(zj-mu)*inv_sig2;
        float d = zj-mu;
        dpp[j] = (d*d - sigma*sigma)*inv_s4;
    }
    float u_val = S - bb*__logf(rho[0]*rho[1]*rho[2]*rho[3]);

    // contractions: H = alpha c c^T + sum_i bet_i B_i B_i^T + sum_k gam_k A_k A_k^T
    float rc=0.0f, scs=0.0f;
    #pragma unroll
    for (int j=0;j<4;j++){ rc += rho[j]*c[j]; scs += c[j]; }
    float rB[4], sB[4], rA[4], sA[4];
    #pragma unroll
    for (int i=0;i<4;i++){
        float r1=0.0f, s=0.0f, r2=0.0f, s2=0.0f;
        #pragma unroll
        for (int j=0;j<4;j++){
            r1 += rho[j]*Bm[i*4+j]; s  += Bm[i*4+j];
            r2 += rho[j]*wx[i*4+j]; s2 += wx[i*4+j];
        }
        rB[i]=r1; sB[i]=s; rA[i]=r2; sA[i]=s2;
    }

    float pde[4], uz[4], uzz[4];
    #pragma unroll
    for (int k=0;k<4;k++){
        float corr = alpha*rc*c[k];
        float hsum = alpha*scs*c[k];
        #pragma unroll
        for (int i=0;i<4;i++){
            corr += bet[i]*rB[i]*Bm[i*4+k];
            hsum += bet[i]*sB[i]*Bm[i*4+k];
            corr += gam[i]*rA[i]*wx[i*4+k];
            hsum += gam[i]*sA[i]*wx[i*4+k];
        }
        float uzk = sp*c[k] - bb*nlp[k];
        uz[k]  = uzk;
        uzz[k] = hsum - bb*dlp;
        // pde WITHOUT the dSdt_sum broadcast (k_fix adds it)
        pde[k] = bb*corr*frcp(rho[k]+1e-5f)
               + 0.5f*uzk*uzk + 0.125f*bb*bb*(nlp[k]*nlp[k] - 2.0f*dpp[k]);
    }

    const int base = b*NIN + gidx*4;
    // pde re-read by k_fix -> normal store (stays in L2)
    *((float4*)(out + base)) = make_float4(pde[0],pde[1],pde[2],pde[3]);
    // uz/u/uzz never re-read on-GPU -> nontemporal (don't pollute L2)
    f32x4 uzv  = { uz[0],  uz[1],  uz[2],  uz[3]  };
    f32x4 uzzv = { uzz[0], uzz[1], uzz[2], uzz[3] };
    __builtin_nontemporal_store(uzv,  (f32x4*)(out + OFF1 + base));
    __builtin_nontemporal_store(u_val, out + OFF2 + b*NG + gidx);
    __builtin_nontemporal_store(uzzv, (f32x4*)(out + OFF3 + base));

    // deterministic block-level dS/dt partial
    __shared__ float sred[256];
    sred[tid] = dsdt_acc;
    __syncthreads();
    if (tid < 128) partial[blockIdx.x*128 + tid] = sred[tid] + sred[tid+128];
}

// Reduce 4096 partials per group -> dsum[g]. 128 blocks x 256 threads.
__global__ __launch_bounds__(256) void k_red(const float* __restrict__ partial,
                                             float* __restrict__ dsum){
    int g = blockIdx.x;
    int tid = threadIdx.x;
    float a = 0.0f;
    for (int i=tid;i<4096;i+=256) a += partial[i*128+g];
    __shared__ float s[256];
    s[tid] = a;
    __syncthreads();
    if (tid < 64){
        a = s[tid] + s[tid+64] + s[tid+128] + s[tid+192];
        #pragma unroll
        for (int o=32;o>0;o>>=1) a += __shfl_down(a, o);
        if (tid==0) dsum[g] = a;
    }
}

// pde += dsum[g]. 4096 blocks x 256 threads, one float4 per thread.
__global__ __launch_bounds__(256) void k_fix(const float* __restrict__ dsum,
                                             float* __restrict__ out){
    const int idx = blockIdx.x*256 + threadIdx.x;   // float4 index; g = idx&127
    const float ds = dsum[threadIdx.x & 127];
    float4* p = ((float4*)out) + idx;
    float4 v = *p;
    v.x += ds; v.y += ds; v.z += ds; v.w += ds;
    *p = v;
}

extern "C" void kernel_launch(void* const* d_in, const int* in_sizes, int n_in,
                              void* d_out, int out_size, void* d_ws, size_t ws_size,
                              hipStream_t stream){
    (void)in_sizes; (void)n_in; (void)out_size; (void)ws_size;
    const float* z     = (const float*)d_in[0];
    const float* ts    = (const float*)d_in[1];
    const float* mu    = (const float*)d_in[2];
    const float* sigma = (const float*)d_in[3];
    const float* Wx    = (const float*)d_in[4];
    const float* bx    = (const float*)d_in[5];
    const float* Wt    = (const float*)d_in[6];
    const float* bt    = (const float*)d_in[7];
    const float* Wt2   = (const float*)d_in[8];
    const float* bt2   = (const float*)d_in[9];
    const float* Wf    = (const float*)d_in[10];
    const float* bf    = (const float*)d_in[11];
    const float* Wo    = (const float*)d_in[12];
    const float* bo    = (const float*)d_in[13];
    const float* beta  = (const float*)d_in[14];
    float* out = (float*)d_out;

    float* ws      = (float*)d_ws;
    float* tv_ws   = ws;            // 512
    float* dtv_ws  = ws + 512;      // 512
    float* consts  = ws + 1024;     // 8
    float* dsum    = ws + 1032;     // 128
    float* partial = ws + 1160;     // 4096*128 = 524288 (2 MB)

    k_pre <<<1,   128, 0, stream>>>(ts, mu, sigma, Wt, bt, Wt2, bt2, tv_ws, dtv_ws, consts);
    k_main<<<4096,256, 0, stream>>>(z, Wx, bx, Wf, bf, Wo, bo, beta, tv_ws, dtv_ws,
                                    consts, partial, out);
    k_red <<<128, 256, 0, stream>>>(partial, dsum);
    k_fix <<<4096,256, 0, stream>>>(dsum, out);
}